// Round 8
// baseline (93.420 us; speedup 1.0000x reference)
//
#include <hip/hip_runtime.h>
#include <stdint.h>
#include <math.h>

#define B_    4
#define HW    36864
#define NPIX  147456
#define C_V   10
#define C_F   64
#define C_D   16
#define C_ALL 90
#define HBINS 32768              // fine bins: key bits 30..16
#define CAP   1536               // bin-b* list capacity (expected ~150)
#define INV   0xFFFFFFFFu

// ---- workspace layout (bytes), 16B-aligned ----
#define OFF_HIST 0u              // 4*HBINS*4 = 524288 (zeroed by k_zero)
#define OFF_KEY  524288u         // NPIX*4 = 589824
#define OFF_G    1114112u        // NPIX
#define OFF_SELX 1261568u        // NPIX (zeroed by k_prep)
#define OFF_HL   1409024u        // 4 uints: per-batch selection threshold

__device__ __forceinline__ uint32_t costOf(uint32_t g) {
    return g == 0u ? 10u : (g == 1u ? 5u : 2u);
}

// budget_per_sample = float32(budget / B); usage,c exact ints ->
// usage+c <= bps  <=>  usage+c <= floor(bps)
__device__ __forceinline__ uint32_t budgetInt(const int* bptr) {
    double bps = (double)bptr[0] / (double)B_;
    float f = (float)bps;
    return (uint32_t)floorf(f);
}

// compare-exchange keeping max in x (descending)
#define CE(x, y) { uint64_t _mn = (x) < (y) ? (x) : (y); \
                   uint64_t _mx = (x) < (y) ? (y) : (x); (x) = _mx; (y) = _mn; }

// K0: zero fine histogram (512 KB)
__global__ void k_zero(uint4* __restrict__ w4) {
    uint32_t i = blockIdx.x * blockDim.x + threadIdx.x;   // [0, 32768)
    w4[i] = make_uint4(0u, 0u, 0u, 0u);
}

// K1: per-pixel best utility / group / sortable key, zero selx, fine hist.
__global__ void k_prep(const float* __restrict__ util, uint4* __restrict__ key4,
                       uint32_t* __restrict__ g4, uint32_t* __restrict__ selx4,
                       uint32_t* __restrict__ hist) {
    int t = blockIdx.x * blockDim.x + threadIdx.x;   // [0, NPIX/4)
    if (t >= NPIX / 4) return;
    const float4* u4 = (const float4*)util + (size_t)t * 3;
    float4 a = u4[0], b4 = u4[1], c4 = u4[2];
    float u[4][3] = { {a.x, a.y, a.z}, {a.w, b4.x, b4.y},
                      {b4.z, b4.w, c4.x}, {c4.y, c4.z, c4.w} };
    uint32_t kk[4]; uint32_t gpack = 0;
    #pragma unroll
    for (int p = 0; p < 4; ++p) {
        float best = u[p][0]; uint32_t g = 0;
        if (u[p][1] > best) { best = u[p][1]; g = 1; }   // strict > = first max
        if (u[p][2] > best) { best = u[p][2]; g = 2; }
        kk[p] = (best > 0.0f) ? (__float_as_uint(best) | 0x80000000u) : 0u;
        gpack |= g << (8 * p);
    }
    key4[t] = make_uint4(kk[0], kk[1], kk[2], kk[3]);
    g4[t] = gpack;
    selx4[t] = 0u;
    int b = (t * 4) / HW;                     // HW % 4 == 0
    #pragma unroll
    for (int p = 0; p < 4; ++p)
        if (kk[p])
            atomicAdd(&hist[(size_t)b * HBINS + ((kk[p] >> 16) & 32767u)],
                      costOf((gpack >> (8 * p)) & 3u));
}

// K2: self-contained per-batch selection. One block per batch, 1024 threads.
// No global atomics, no fences, no cross-block traffic (the R7 lesson:
// cross-XCD coordination cost 43us; this kernel has none).
// Phase A: hist cumsum (reg-resident chunks + shfl scans) -> b2/usage/hl.
// Phase B: one vectorized key scan -> LDS bin-b* list + reg tail candidates.
// Phase C: LDS rank-sort + serial greedy + exact <=5-pick tail replay.
__global__ __launch_bounds__(1024) void k_sel(const uint32_t* __restrict__ key,
                                              const uint8_t* __restrict__ g,
                                              const uint32_t* __restrict__ hist,
                                              const int* __restrict__ budget_ptr,
                                              uint8_t* __restrict__ selx,
                                              uint32_t* __restrict__ hl_out) {
    int b = blockIdx.x;
    int t = threadIdx.x;
    int lane = t & 63, wv = t >> 6;
    uint32_t budget = budgetInt(budget_ptr);
    const uint32_t* hb = hist + (size_t)b * HBINS;

    __shared__ uint32_t wsum[16];
    __shared__ uint32_t sh_b2, sh_usage, sh_n;
    __shared__ uint64_t e[CAP];
    __shared__ uint64_t s[CAP];
    __shared__ uint64_t red5[16];
    __shared__ uint64_t red2[16][4];

    if (t == 0) { sh_b2 = INV; sh_usage = 0u; sh_n = 0u; }

    // ---- Phase A: descending cumsum over 32768 bins ----
    // chunk t covers bins [32736-32t, 32767-32t]; chunk order = descending bins
    uint4 hv[8];
    const uint4* h4 = (const uint4*)(hb + (32736 - 32 * t));
    #pragma unroll
    for (int j = 0; j < 8; ++j) hv[j] = h4[j];
    uint32_t cs = 0;
    #pragma unroll
    for (int j = 0; j < 8; ++j) cs += hv[j].x + hv[j].y + hv[j].z + hv[j].w;
    uint32_t v = cs;
    #pragma unroll
    for (int off = 1; off < 64; off <<= 1) {          // wave inclusive scan
        uint32_t o = __shfl_up(v, off);
        if (lane >= off) v += o;
    }
    if (lane == 63) wsum[wv] = v;
    __syncthreads();                                   // also covers sh_* init
    if (t < 16) {                                      // scan the 16 wave sums
        uint32_t w = wsum[t];
        #pragma unroll
        for (int off = 1; off < 16; off <<= 1) {
            uint32_t o = __shfl_up(w, off);
            if (t >= off) w += o;
        }
        wsum[t] = w;
    }
    __syncthreads();
    uint32_t incl = v + (wv ? wsum[wv - 1] : 0u);
    uint32_t excl = incl - cs;
    if (excl <= budget && incl > budget) {             // exactly one finder
        uint32_t vals[32];
        #pragma unroll
        for (int j = 0; j < 8; ++j) {
            vals[4 * j + 0] = hv[j].x; vals[4 * j + 1] = hv[j].y;
            vals[4 * j + 2] = hv[j].z; vals[4 * j + 3] = hv[j].w;
        }
        uint32_t cum = excl;
        #pragma unroll
        for (int a = 31; a >= 0; --a) {                // walk bins descending
            uint32_t val = vals[a];
            if (cum + val > budget) { sh_b2 = (uint32_t)(32736 - 32 * t + a);
                                      sh_usage = cum; break; }
            cum += val;
        }
    }
    __syncthreads();
    uint32_t b2 = sh_b2;
    if (t == 0) {
        uint32_t hl;
        if (b2 == INV) hl = 1u;                        // no crossing: all valid
        else { uint32_t bs = b2 + 32768u;
               hl = (bs >= 65535u) ? INV : ((bs + 1u) << 16); }
        hl_out[b] = hl;
    }
    if (b2 == INV) return;                             // block-uniform exit

    // ---- Phase B: single vectorized key scan ----
    const uint4*     k4  = (const uint4*)(key + (size_t)b * HW);   // 9216 groups
    const uint32_t*  g4p = (const uint32_t*)(g + (size_t)b * HW);
    uint64_t m5 = 0, a0 = 0, a1 = 0, a2 = 0, a3 = 0;
    #pragma unroll
    for (int it = 0; it < 9; ++it) {
        int gi = t + it * 1024;                        // [0, 9216)
        uint4 kk = k4[gi];
        uint32_t gp = g4p[gi];
        uint32_t kv[4] = { kk.x, kk.y, kk.z, kk.w };
        #pragma unroll
        for (int p = 0; p < 4; ++p) {
            uint32_t k = kv[p];
            if (!k) continue;
            uint32_t bin = (k >> 16) & 32767u;
            uint32_t gg = (gp >> (8 * p)) & 3u;
            uint32_t pix = (uint32_t)(gi * 4 + p);
            if (bin == b2) {
                uint32_t idx = atomicAdd(&sh_n, 1u);   // LDS atomic: cheap
                if (idx < CAP)   // asc key: (~k, pix) -> utility desc, pix asc
                    e[idx] = ((uint64_t)(~k) << 32) | ((uint64_t)pix << 2)
                           | (uint64_t)gg;
            } else if (bin < b2 && gg) {               // cost-10 never fits (r<=9)
                uint64_t m = ((uint64_t)k << 18)
                           | ((uint64_t)(65535u - pix) << 2) | (uint64_t)gg;
                if (gg == 1u) { if (m > m5) m5 = m; }
                else if (m > a3) {                     // sorted insert, static idx
                    if      (m > a0) { a3 = a2; a2 = a1; a1 = a0; a0 = m; }
                    else if (m > a1) { a3 = a2; a2 = a1; a1 = m; }
                    else if (m > a2) { a3 = a2; a2 = m; }
                    else             { a3 = m; }
                }
            }
        }
    }
    #pragma unroll
    for (int off = 32; off; off >>= 1) {               // wave reduce tails
        uint64_t o5 = __shfl_down(m5, off);
        if (o5 > m5) m5 = o5;
        uint64_t b0 = __shfl_down(a0, off), b1 = __shfl_down(a1, off),
                 b2_ = __shfl_down(a2, off), b3 = __shfl_down(a3, off);
        CE(a0, b3); CE(a1, b2_); CE(a2, b1); CE(a3, b0);
        CE(a0, a2); CE(a1, a3); CE(a0, a1); CE(a2, a3);
    }
    if (lane == 0) {
        red5[wv] = m5;
        red2[wv][0] = a0; red2[wv][1] = a1; red2[wv][2] = a2; red2[wv][3] = a3;
    }
    __syncthreads();

    // ---- Phase C: rank-sort bin-b* list, then serial greedy + tail ----
    int n = (int)(sh_n < (uint32_t)CAP ? sh_n : (uint32_t)CAP);
    for (int i = t; i < n; i += 1024) {                // rank sort (keys distinct)
        uint64_t ei = e[i];
        int rk = 0;
        for (int j = 0; j < n; ++j) rk += (e[j] < ei);
        s[rk] = ei;
    }
    __syncthreads();
    if (t == 0) {
        // merge 16 waves' tail candidates
        uint64_t g5 = 0, c0 = 0, c1 = 0, c2 = 0, c3 = 0;
        for (int wq = 0; wq < 16; ++wq) {
            if (red5[wq] > g5) g5 = red5[wq];
            #pragma unroll
            for (int q = 0; q < 4; ++q) {
                uint64_t m = red2[wq][q];
                if (m > c3) {
                    if      (m > c0) { c3 = c2; c2 = c1; c1 = c0; c0 = m; }
                    else if (m > c1) { c3 = c2; c2 = c1; c1 = m; }
                    else if (m > c2) { c3 = c2; c2 = m; }
                    else             { c3 = m; }
                }
            }
        }
        // serial greedy within bin b*
        uint32_t usage = sh_usage;
        uint8_t* sx = selx + (size_t)b * HW;
        for (int i = 0; i < n; ++i) {
            uint64_t ei = s[i];
            uint32_t c = costOf((uint32_t)(ei & 3u));
            if (usage + c <= budget) { usage += c; sx[(ei >> 2) & 0xFFFFu] = 1; }
        }
        // exact <=5-pick tail replay below bin b*
        uint64_t c5[5] = { g5, c0, c1, c2, c3 };
        for (int i = 1; i < 5; ++i) {
            uint64_t x = c5[i]; int j = i;
            while (j > 0 && c5[j - 1] < x) { c5[j] = c5[j - 1]; --j; }
            c5[j] = x;
        }
        uint32_t r = budget - usage;                   // provably <= 9
        for (int i = 0; i < 5; ++i) {
            uint64_t m = c5[i];
            if (!m) break;
            uint32_t c = costOf((uint32_t)(m & 3u));
            if (c <= r) {
                r -= c;
                uint32_t pix = 65535u - (uint32_t)((m >> 2) & 0xFFFFu);
                sx[pix] = 1;
            }
        }
    }
}

// K3: masked sparse BEV + sel_idx output (c==0 blocks), float4-vectorized.
__global__ void k_sparse(const float* __restrict__ collab, const uint4* __restrict__ key4,
                         const uint32_t* __restrict__ g4, const uint32_t* __restrict__ selx4,
                         const uint32_t* __restrict__ hl_arr,
                         float* __restrict__ out, float* __restrict__ selOut) {
    int tid = blockIdx.x * blockDim.x + threadIdx.x;   // [0, HW/4)
    int c = blockIdx.y, b = blockIdx.z;
    int cls = (c < C_V) ? 0 : ((c < C_V + C_F) ? 1 : 2);
    uint32_t hl = hl_arr[b];                           // >= 1 always
    size_t p4 = (size_t)b * (HW / 4) + (size_t)tid;
    uint4 kk = key4[p4];
    uint32_t gg = g4[p4];
    uint32_t sx = selx4[p4];
    int sc[4];
    uint32_t kv[4] = { kk.x, kk.y, kk.z, kk.w };
    #pragma unroll
    for (int p = 0; p < 4; ++p) {
        bool se = (kv[p] >= hl) || (((sx >> (8 * p)) & 0xFFu) != 0u);
        sc[p] = se ? (int)((gg >> (8 * p)) & 3u) : -1;
    }
    size_t co = ((size_t)(b * C_ALL + c)) * HW + (size_t)tid * 4;
    float4 v = *(const float4*)(collab + co);
    float4 o;
    o.x = (sc[0] == cls) ? v.x : 0.0f;
    o.y = (sc[1] == cls) ? v.y : 0.0f;
    o.z = (sc[2] == cls) ? v.z : 0.0f;
    o.w = (sc[3] == cls) ? v.w : 0.0f;
    *(float4*)(out + co) = o;
    if (c == 0) {
        float4 sf = make_float4((float)sc[0], (float)sc[1], (float)sc[2], (float)sc[3]);
        ((float4*)selOut)[p4] = sf;
    }
}

extern "C" void kernel_launch(void* const* d_in, const int* in_sizes, int n_in,
                              void* d_out, int out_size, void* d_ws, size_t ws_size,
                              hipStream_t stream) {
    (void)in_sizes; (void)n_in; (void)out_size; (void)ws_size;
    const float* collab = (const float*)d_in[0];
    const float* util   = (const float*)d_in[1];
    const int*   budget = (const int*)d_in[2];

    uint8_t*  ws   = (uint8_t*)d_ws;
    uint32_t* hist = (uint32_t*)(ws + OFF_HIST);
    uint32_t* key  = (uint32_t*)(ws + OFF_KEY);
    uint8_t*  g    = ws + OFF_G;
    uint8_t*  selx = ws + OFF_SELX;
    uint32_t* hl   = (uint32_t*)(ws + OFF_HL);

    float* outSparse = (float*)d_out;
    float* outSel    = outSparse + (size_t)B_ * C_ALL * HW;

    k_zero <<<HBINS * 4 / 4 / 256, 256, 0, stream>>>((uint4*)hist);
    k_prep <<<NPIX / 4 / 256, 256, 0, stream>>>(util, (uint4*)key, (uint32_t*)g,
                                                (uint32_t*)selx, hist);
    k_sel  <<<B_, 1024, 0, stream>>>(key, g, hist, budget, selx, hl);
    dim3 gridSP(HW / 4 / 256, C_ALL, B_);
    k_sparse<<<gridSP, 256, 0, stream>>>(collab, (const uint4*)key, (const uint32_t*)g,
                                         (const uint32_t*)selx, hl,
                                         outSparse, outSel);
}